// Round 12
// baseline (332.436 us; speedup 1.0000x reference)
//
#include <hip/hip_runtime.h>
#include <hip/hip_bf16.h>
#include <hip/hip_fp16.h>
#include <math.h>

#define BB 64
#define OO 32
#define II 2048
#define DD 16
#define CAPS_EPS 1e-12f
#define T_CONST 5.6312118f   // ln(0.9*31) - ln(0.1)

#define TIS 8                // i per s0w block (strip) -> 256 w-strips
#define NSTRIP_W 256         // II/TIS (s0w partial strips)
#define SLEN 16              // i per dpass/spass strip (16 proven)
#define NSTRIP 128           // II/SLEN (stream strips)

// workspace float offsets (total ~41.6M floats = 166 MB; ws >= 201 MB proven)
#define OFF_DSUM  0ULL
#define OFF_V     16ULL        // (unused slot kept for layout stability)
#define OFF_UNORM 32784ULL     // 131072 f32: unorm [I][B]
#define OFF_UBF   163856ULL    // 1048576 f32 slots: u bf16 [I][B][16]
#define OFF_Y     1212432ULL   // 33554432 f32 slots: uhat_scaled fp16 [I][O][B][D] (nontemporal)
#define OFF_DD    34766864ULL  // 2097152 f32 slots: d fp16 [I][O][B]
#define OFF_TMAX  36864016ULL  // 131072 f32: rowmax of t*d [I][B]
#define OFF_TDEN  36995088ULL  // 131072 f32: denom [I][B]
#define OFF_PART  37126160ULL  // 4194304 f32 slots: part fp16 [<=256][O][B][D]
#define OFF_VT    41320464ULL  // 32768 f32: v transposed [O][B][D]
#define OFF_P2    41353232ULL  // 262144 f32: p2 [8][32768]

typedef __attribute__((ext_vector_type(8))) short bf16x8;
typedef __attribute__((ext_vector_type(4))) float f32x4;
typedef unsigned int u32x2 __attribute__((ext_vector_type(2)));
typedef unsigned int u32x4 __attribute__((ext_vector_type(4)));

union AU { bf16x8 v; unsigned short h[8]; uint4 u4; };
union YU { __half h[4]; u32x2 u2; };
union YL { u32x4 q[2]; __half h[16]; };   // 32 B = 16 halves
union PS { __half h[16]; uint4 u4[2]; };
union P4 { __half h[4]; uint2 u2; };

__device__ __forceinline__ unsigned short f2bf(float x) {
    __hip_bfloat16 h = __float2bfloat16(x);
    unsigned short s; __builtin_memcpy(&s, &h, 2); return s;
}

// -------- uprep: u -> bf16 [i][b][16], unorm[i][b], zero dsum --------
__global__ __launch_bounds__(256) void uprep_kernel(
    const float* __restrict__ u, float* __restrict__ ws)
{
    const int gid = blockIdx.x * 256 + threadIdx.x;   // 131072
    if (gid < 2) ws[OFF_DSUM + gid] = 0.f;
    const int i = gid >> 6, b = gid & 63;

    const float4* up = reinterpret_cast<const float4*>(u + ((size_t)b * II + i) * DD);
    float4 t0 = up[0], t1 = up[1], t2 = up[2], t3 = up[3];
    float un2 = t0.x*t0.x + t0.y*t0.y + t0.z*t0.z + t0.w*t0.w
              + t1.x*t1.x + t1.y*t1.y + t1.z*t1.z + t1.w*t1.w
              + t2.x*t2.x + t2.y*t2.y + t2.z*t2.z + t2.w*t2.w
              + t3.x*t3.x + t3.y*t3.y + t3.z*t3.z + t3.w*t3.w;
    ws[OFF_UNORM + (size_t)i * 64 + b] = __builtin_amdgcn_sqrtf(un2);

    AU a0, a1;
    a0.h[0]=f2bf(t0.x); a0.h[1]=f2bf(t0.y); a0.h[2]=f2bf(t0.z); a0.h[3]=f2bf(t0.w);
    a0.h[4]=f2bf(t1.x); a0.h[5]=f2bf(t1.y); a0.h[6]=f2bf(t1.z); a0.h[7]=f2bf(t1.w);
    a1.h[0]=f2bf(t2.x); a1.h[1]=f2bf(t2.y); a1.h[2]=f2bf(t2.z); a1.h[3]=f2bf(t2.w);
    a1.h[4]=f2bf(t3.x); a1.h[5]=f2bf(t3.y); a1.h[6]=f2bf(t3.z); a1.h[7]=f2bf(t3.w);
    unsigned short* ubf = (unsigned short*)(ws + OFF_UBF);
    uint4* dst = reinterpret_cast<uint4*>(ubf + ((size_t)i * 64 + b) * 16);
    dst[0] = a0.u4; dst[1] = a1.u4;
}

// -------- s0w: W fp32 -> MFMA uhat -> scaled fp16 Y (NT) + fp16 s0 partials --------
__global__ __launch_bounds__(256) void s0w_kernel(
    const float* __restrict__ W, float* __restrict__ ws)
{
    const int strip = blockIdx.x;           // NSTRIP_W strips of TIS=8 i's
    const int og   = blockIdx.y;
    const int wave = threadIdx.x >> 6;
    const int lane = threadIdx.x & 63;
    const int o    = og * 4 + wave;
    const int q    = lane >> 4;
    const int n    = lane & 15;

    const unsigned short* ubf = (const unsigned short*)(ws + OFF_UBF);
    const float* unorm = ws + OFF_UNORM;
    __half* Y = (__half*)(ws + OFF_Y);
    __half* part_h = (__half*)(ws + OFF_PART);

    f32x4 s_acc[4];
    #pragma unroll
    for (int g = 0; g < 4; ++g) s_acc[g] = (f32x4){0.f, 0.f, 0.f, 0.f};

    for (int ii = 0; ii < TIS; ++ii) {
        const int i = strip * TIS + ii;

        AU au; au.u4 = make_uint4(0, 0, 0, 0);
        if (q < 2) {
            const float* wp = W + (((size_t)o * II + i) * 16 + n) * 16 + q * 8;
            float4 w0 = *(const float4*)(wp);
            float4 w1 = *(const float4*)(wp + 4);
            au.h[0]=f2bf(w0.x); au.h[1]=f2bf(w0.y); au.h[2]=f2bf(w0.z); au.h[3]=f2bf(w0.w);
            au.h[4]=f2bf(w1.x); au.h[5]=f2bf(w1.y); au.h[6]=f2bf(w1.z); au.h[7]=f2bf(w1.w);
        }

        f32x4 d4[4];
        #pragma unroll
        for (int g = 0; g < 4; ++g) {
            AU bu;
            bu.u4 = *reinterpret_cast<const uint4*>(
                ubf + ((size_t)i * 64 + g * 16 + n) * 16 + (q & 1) * 8);
            d4[g] = __builtin_amdgcn_mfma_f32_16x16x32_bf16(
                au.v, bu.v, (f32x4){0.f, 0.f, 0.f, 0.f}, 0, 0, 0);
        }

        #pragma unroll
        for (int g = 0; g < 4; ++g) {
            float n2 = d4[g][0]*d4[g][0] + d4[g][1]*d4[g][1]
                     + d4[g][2]*d4[g][2] + d4[g][3]*d4[g][3];
            n2 += __shfl_xor(n2, 16);
            n2 += __shfl_xor(n2, 32);
            const float rsq  = __builtin_amdgcn_rsqf(n2 + CAPS_EPS);
            const float rawn = n2 * rsq;
            const float un = unorm[(size_t)i * 64 + g * 16 + n];
            const float scale = fminf(rawn, un) * rsq;    // min/rawn

            // scaled uhat -> fp16, nontemporal store (Y is read-once-per-pass, bypass L3)
            YU yu;
            yu.h[0] = __float2half(scale * d4[g][0]);
            yu.h[1] = __float2half(scale * d4[g][1]);
            yu.h[2] = __float2half(scale * d4[g][2]);
            yu.h[3] = __float2half(scale * d4[g][3]);
            __builtin_nontemporal_store(yu.u2, reinterpret_cast<u32x2*>(
                Y + (((size_t)i * OO + o) * 64 + g * 16 + n) * 16 + q * 4));

            const float cs = 0.03125f * scale;            // c = 1/32 at r=0
            s_acc[g][0] += cs * d4[g][0];
            s_acc[g][1] += cs * d4[g][1];
            s_acc[g][2] += cs * d4[g][2];
            s_acc[g][3] += cs * d4[g][3];
        }
    }

    #pragma unroll
    for (int g = 0; g < 4; ++g) {
        P4 pu;
        pu.h[0] = __float2half(s_acc[g][0]);
        pu.h[1] = __float2half(s_acc[g][1]);
        pu.h[2] = __float2half(s_acc[g][2]);
        pu.h[3] = __float2half(s_acc[g][3]);
        *reinterpret_cast<uint2*>(
            part_h + (((size_t)strip * OO + o) * 64 + g * 16 + n) * 16 + q * 4) = pu.u2;
    }
}

// -------- fpart: parallel strip reduction, part fp16 -> p2[8][32768] f32 --------
template<int NS>
__global__ __launch_bounds__(256) void fpart_kernel(float* __restrict__ ws)
{
    const int tid = blockIdx.x * 256 + threadIdx.x;   // 262144
    const int g = tid >> 15;                          // 8 groups
    const int x = tid & 32767;                        // part inner index
    const __half* part_h = (const __half*)(ws + OFF_PART);
    constexpr int NSG = NS / 8;
    float s = 0.f;
    #pragma unroll
    for (int k = 0; k < NSG; ++k)
        s += __half2float(part_h[(size_t)(g * NSG + k) * 32768 + x]);
    ws[OFF_P2 + (size_t)g * 32768 + x] = s;
}

// -------- fsquash: sum p2 (+bias) -> squash -> v --------
// FINAL=0: write vt [O][B][D]; FINAL=1: write out [B][O][D]
template<int FINAL>
__global__ __launch_bounds__(256) void fsquash_kernel(
    float* __restrict__ ws, const float* __restrict__ bias,
    float* __restrict__ out)
{
    const int tid = blockIdx.x * 256 + threadIdx.x;  // 32768: b*512 + o*16 + d
    const int b = tid >> 9, o = (tid >> 4) & 31, d = tid & 15;
    const size_t px = ((size_t)o * 64 + b) * 16 + d;   // vt index
    float s = bias[tid & 511];
    #pragma unroll
    for (int g = 0; g < 8; ++g)
        s += ws[OFF_P2 + (size_t)g * 32768 + px];
    float n2 = s * s;
    #pragma unroll
    for (int off = 1; off < 16; off <<= 1) n2 += __shfl_xor(n2, off);
    const float val = s * n2 * __builtin_amdgcn_rcpf(1.f + n2)
                        * __builtin_amdgcn_rsqf(n2 + CAPS_EPS);
    if (FINAL) out[tid] = val;
    else       ws[OFF_VT + px] = val;
}

// -------- dpass: stream Y (NT loads), dist fp16, block-reduced dsum --------
template<int SLOT>
__global__ __launch_bounds__(256) void dpass_kernel(float* __restrict__ ws)
{
    const int strip = blockIdx.x;           // NSTRIP
    const int og    = blockIdx.y;           // 8
    const int wave  = threadIdx.x >> 6;
    const int b     = threadIdx.x & 63;
    const int o     = og * 4 + wave;

    const __half* Y  = (const __half*)(ws + OFF_Y);
    const float* vt  = ws + OFF_VT;
    __half* dws = (__half*)(ws + OFF_DD);

    // coalesced v preload: 4 x float4 from [O][B][D]
    float v[16];
    {
        const float4* vp = reinterpret_cast<const float4*>(
            vt + ((size_t)o * 64 + b) * 16);
        float4 a = vp[0], c = vp[1], e = vp[2], f = vp[3];
        v[0]=a.x; v[1]=a.y; v[2]=a.z; v[3]=a.w;
        v[4]=c.x; v[5]=c.y; v[6]=c.z; v[7]=c.w;
        v[8]=e.x; v[9]=e.y; v[10]=e.z; v[11]=e.w;
        v[12]=f.x; v[13]=f.y; v[14]=f.z; v[15]=f.w;
    }
    float vn2 = 0.f;
    #pragma unroll
    for (int k = 0; k < 16; ++k) vn2 += v[k] * v[k];

    float acc = 0.f;
    #pragma unroll 4
    for (int s = 0; s < SLEN; ++s) {
        const int i = strip * SLEN + s;
        const u32x4* yp = reinterpret_cast<const u32x4*>(
            Y + (((size_t)i * OO + o) * 64 + b) * 16);
        YL yl;
        yl.q[0] = __builtin_nontemporal_load(yp);
        yl.q[1] = __builtin_nontemporal_load(yp + 1);
        float dot = 0.f, yn2 = 0.f;
        #pragma unroll
        for (int k = 0; k < 16; ++k) {
            const float y = __half2float(yl.h[k]);
            dot += v[k] * y;
            yn2 += y * y;
        }
        const float dd2 = fmaxf(vn2 - 2.f * dot + yn2, 0.f);
        const __half dh = __float2half(__builtin_amdgcn_sqrtf(dd2));
        dws[((size_t)i * OO + o) * 64 + b] = dh;
        acc += __half2float(dh);
    }

    #pragma unroll
    for (int off = 32; off > 0; off >>= 1) acc += __shfl_down(acc, off);
    __shared__ float red[4];
    if ((threadIdx.x & 63) == 0) red[wave] = acc;
    __syncthreads();
    if (threadIdx.x == 0)
        atomicAdd(&ws[OFF_DSUM + SLOT], red[0] + red[1] + red[2] + red[3]);
}

// -------- csoft: rowmax + denom of softmax_o(t*d) per (i,b) --------
template<int SLOT>
__global__ __launch_bounds__(256) void csoft_kernel(float* __restrict__ ws)
{
    const int gid = blockIdx.x * 256 + threadIdx.x;   // 131072
    const int i = gid >> 6, b = gid & 63;

    const __half* dws = (const __half*)(ws + OFF_DD);
    const float dsum = ws[OFF_DSUM + SLOT];
    const float tval = T_CONST * __builtin_amdgcn_rcpf(
        -0.5f * dsum * (1.0f / 4194304.0f) + 1e-12f);

    float dv[OO];
    #pragma unroll
    for (int o = 0; o < OO; ++o)
        dv[o] = tval * __half2float(dws[((size_t)i * OO + o) * 64 + b]);
    float m = -1e30f;
    #pragma unroll
    for (int o = 0; o < OO; ++o) m = fmaxf(m, dv[o]);
    float den = 0.f;
    #pragma unroll
    for (int o = 0; o < OO; ++o) den += __expf(dv[o] - m);
    ws[OFF_TMAX + (size_t)i * 64 + b] = m;
    ws[OFF_TDEN + (size_t)i * 64 + b] = den;
}

// -------- spass: stream Y (NT loads); fp16 partials --------
template<int SLOT>
__global__ __launch_bounds__(256) void spass_kernel(float* __restrict__ ws)
{
    const int strip = blockIdx.x;
    const int og    = blockIdx.y;
    const int wave  = threadIdx.x >> 6;
    const int b     = threadIdx.x & 63;
    const int o     = og * 4 + wave;

    const __half* Y = (const __half*)(ws + OFF_Y);
    const __half* dws = (const __half*)(ws + OFF_DD);
    const float* tmax = ws + OFF_TMAX;
    const float* tden = ws + OFF_TDEN;
    __half* part_h = (__half*)(ws + OFF_PART);

    const float dsum = ws[OFF_DSUM + SLOT];
    const float tval = T_CONST * __builtin_amdgcn_rcpf(
        -0.5f * dsum * (1.0f / 4194304.0f) + 1e-12f);

    float acc[16];
    #pragma unroll
    for (int k = 0; k < 16; ++k) acc[k] = 0.f;

    #pragma unroll 4
    for (int s = 0; s < SLEN; ++s) {
        const int i = strip * SLEN + s;
        const u32x4* yp = reinterpret_cast<const u32x4*>(
            Y + (((size_t)i * OO + o) * 64 + b) * 16);
        YL yl;
        yl.q[0] = __builtin_nontemporal_load(yp);
        yl.q[1] = __builtin_nontemporal_load(yp + 1);
        const float d  = __half2float(dws[((size_t)i * OO + o) * 64 + b]);
        const float m  = tmax[(size_t)i * 64 + b];
        const float dn = tden[(size_t)i * 64 + b];
        const float p = __expf(tval * d - m) * __builtin_amdgcn_rcpf(dn);
        #pragma unroll
        for (int k = 0; k < 16; ++k)
            acc[k] += p * __half2float(yl.h[k]);
    }

    // fp16 coalesced partial store: part[strip][o][b][k] (wave = 2KB contig)
    PS su;
    #pragma unroll
    for (int k = 0; k < 16; ++k) su.h[k] = __float2half(acc[k]);
    uint4* pp = reinterpret_cast<uint4*>(
        part_h + (((size_t)strip * OO + o) * 64 + b) * 16);
    pp[0] = su.u4[0];
    pp[1] = su.u4[1];
}

// -------- transpose: c = softmax recompute, [I][O][B] -> out [B][O][I] --------
__global__ __launch_bounds__(256) void transpose_kernel(
    const float* __restrict__ ws, float* __restrict__ dst)
{
    __shared__ float tile[32][65];
    const __half* dws = (const __half*)(ws + OFF_DD);
    const float* tmax = ws + OFF_TMAX;
    const float* tden = ws + OFF_TDEN;
    const float dsum = ws[OFF_DSUM + 1];
    const float tval = T_CONST * __builtin_amdgcn_rcpf(
        -0.5f * dsum * (1.0f / 4194304.0f) + 1e-12f);

    const int o  = blockIdx.y;
    const int i0 = blockIdx.x * 32;
    #pragma unroll
    for (int k = 0; k < 8; ++k) {
        const int lin = k * 256 + threadIdx.x;
        const int r = lin >> 6, b = lin & 63;
        const int i = i0 + r;
        const float d = __half2float(dws[((size_t)i * OO + o) * 64 + b]);
        tile[r][b] = __expf(tval * d - tmax[(size_t)i * 64 + b])
                   * __builtin_amdgcn_rcpf(tden[(size_t)i * 64 + b]);
    }
    __syncthreads();
    #pragma unroll
    for (int k = 0; k < 8; ++k) {
        const int lin = k * 256 + threadIdx.x;
        const int b = lin >> 5, r = lin & 31;
        dst[((size_t)b * OO + o) * II + i0 + r] = tile[r][b];
    }
}

extern "C" void kernel_launch(void* const* d_in, const int* in_sizes, int n_in,
                              void* d_out, int out_size, void* d_ws, size_t ws_size,
                              hipStream_t stream) {
    const float* u    = (const float*)d_in[0];
    const float* W    = (const float*)d_in[1];
    const float* bias = (const float*)d_in[2];
    float* out = (float*)d_out;
    float* ws  = (float*)d_ws;

    float* cout = out + (size_t)BB * OO * DD;

    dim3 blk(256);
    dim3 grid_w(NSTRIP_W, 8);     // s0w: 2048 blocks
    dim3 grid_s(NSTRIP, 8);       // dpass/spass: 1024 blocks (proven)

    uprep_kernel<<<512, blk, 0, stream>>>(u, ws);
    s0w_kernel<<<grid_w, blk, 0, stream>>>(W, ws);
    fpart_kernel<NSTRIP_W><<<1024, blk, 0, stream>>>(ws);
    fsquash_kernel<0><<<128, blk, 0, stream>>>(ws, bias, out);
    dpass_kernel<0><<<grid_s, blk, 0, stream>>>(ws);
    csoft_kernel<0><<<512, blk, 0, stream>>>(ws);
    spass_kernel<0><<<grid_s, blk, 0, stream>>>(ws);
    fpart_kernel<NSTRIP><<<1024, blk, 0, stream>>>(ws);
    fsquash_kernel<0><<<128, blk, 0, stream>>>(ws, bias, out);
    dpass_kernel<1><<<grid_s, blk, 0, stream>>>(ws);
    csoft_kernel<1><<<512, blk, 0, stream>>>(ws);
    spass_kernel<1><<<grid_s, blk, 0, stream>>>(ws);
    fpart_kernel<NSTRIP><<<1024, blk, 0, stream>>>(ws);
    fsquash_kernel<1><<<128, blk, 0, stream>>>(ws, bias, out);
    transpose_kernel<<<dim3(64, 32), blk, 0, stream>>>(ws, cout);
}

// Round 13
// 291.540 us; speedup vs baseline: 1.1403x; 1.1403x over previous
//
#include <hip/hip_runtime.h>
#include <hip/hip_bf16.h>
#include <hip/hip_fp16.h>
#include <math.h>

#define BB 64
#define OO 32
#define II 2048
#define DD 16
#define CAPS_EPS 1e-12f
#define T_CONST 5.6312118f   // ln(0.9*31) - ln(0.1)

#define TIS 8                // i per s0w block (strip) -> 256 w-strips
#define NSTRIP_W 256         // II/TIS (s0w partial strips)
#define SLEN 16              // i per dpass/spass strip (16 proven; 8 regresses r6/r9)
#define NSTRIP 128           // II/SLEN (stream strips)

// workspace float offsets (total ~41.6M floats = 166 MB; ws >= 201 MB proven)
#define OFF_DSUM  0ULL
#define OFF_V     16ULL        // (unused slot kept for layout stability)
#define OFF_UNORM 32784ULL     // 131072 f32: unorm [I][B]
#define OFF_UBF   163856ULL    // 1048576 f32 slots: u bf16 [I][B][16]
#define OFF_Y     1212432ULL   // 33554432 f32 slots: uhat_scaled fp16 [I][O][B][D]
#define OFF_DD    34766864ULL  // 2097152 f32 slots: d fp16 [I][O][B]
#define OFF_TMAX  36864016ULL  // 131072 f32: rowmax of t*d [I][B]
#define OFF_TDEN  36995088ULL  // 131072 f32: denom [I][B]
#define OFF_PART  37126160ULL  // 4194304 f32 slots: part fp16 [<=256][O][B][D]
#define OFF_VT    41320464ULL  // 32768 f32: v transposed [O][B][D]
#define OFF_P2    41353232ULL  // 262144 f32: p2 [8][32768]

typedef __attribute__((ext_vector_type(8))) short bf16x8;
typedef __attribute__((ext_vector_type(4))) float f32x4;

union AU { bf16x8 v; unsigned short h[8]; uint4 u4; };
union YU { __half h[4]; uint2 u2; };
union YL { uint4 u4[2]; __half h[16]; };   // 32 B = 16 halves
union PS { __half h[16]; uint4 u4[2]; };
union P4 { __half h[4]; uint2 u2; };

__device__ __forceinline__ unsigned short f2bf(float x) {
    __hip_bfloat16 h = __float2bfloat16(x);
    unsigned short s; __builtin_memcpy(&s, &h, 2); return s;
}

// -------- uprep: u -> bf16 [i][b][16], unorm[i][b], zero dsum --------
__global__ __launch_bounds__(256) void uprep_kernel(
    const float* __restrict__ u, float* __restrict__ ws)
{
    const int gid = blockIdx.x * 256 + threadIdx.x;   // 131072
    if (gid < 2) ws[OFF_DSUM + gid] = 0.f;
    const int i = gid >> 6, b = gid & 63;

    const float4* up = reinterpret_cast<const float4*>(u + ((size_t)b * II + i) * DD);
    float4 t0 = up[0], t1 = up[1], t2 = up[2], t3 = up[3];
    float un2 = t0.x*t0.x + t0.y*t0.y + t0.z*t0.z + t0.w*t0.w
              + t1.x*t1.x + t1.y*t1.y + t1.z*t1.z + t1.w*t1.w
              + t2.x*t2.x + t2.y*t2.y + t2.z*t2.z + t2.w*t2.w
              + t3.x*t3.x + t3.y*t3.y + t3.z*t3.z + t3.w*t3.w;
    ws[OFF_UNORM + (size_t)i * 64 + b] = __builtin_amdgcn_sqrtf(un2);

    AU a0, a1;
    a0.h[0]=f2bf(t0.x); a0.h[1]=f2bf(t0.y); a0.h[2]=f2bf(t0.z); a0.h[3]=f2bf(t0.w);
    a0.h[4]=f2bf(t1.x); a0.h[5]=f2bf(t1.y); a0.h[6]=f2bf(t1.z); a0.h[7]=f2bf(t1.w);
    a1.h[0]=f2bf(t2.x); a1.h[1]=f2bf(t2.y); a1.h[2]=f2bf(t2.z); a1.h[3]=f2bf(t2.w);
    a1.h[4]=f2bf(t3.x); a1.h[5]=f2bf(t3.y); a1.h[6]=f2bf(t3.z); a1.h[7]=f2bf(t3.w);
    unsigned short* ubf = (unsigned short*)(ws + OFF_UBF);
    uint4* dst = reinterpret_cast<uint4*>(ubf + ((size_t)i * 64 + b) * 16);
    dst[0] = a0.u4; dst[1] = a1.u4;
}

// -------- s0w: W fp32 -> MFMA uhat -> scaled fp16 Y + fp16 s0 partials --------
__global__ __launch_bounds__(256) void s0w_kernel(
    const float* __restrict__ W, float* __restrict__ ws)
{
    const int strip = blockIdx.x;           // NSTRIP_W strips of TIS=8 i's
    const int og   = blockIdx.y;
    const int wave = threadIdx.x >> 6;
    const int lane = threadIdx.x & 63;
    const int o    = og * 4 + wave;
    const int q    = lane >> 4;
    const int n    = lane & 15;

    const unsigned short* ubf = (const unsigned short*)(ws + OFF_UBF);
    const float* unorm = ws + OFF_UNORM;
    __half* Y = (__half*)(ws + OFF_Y);
    __half* part_h = (__half*)(ws + OFF_PART);

    f32x4 s_acc[4];
    #pragma unroll
    for (int g = 0; g < 4; ++g) s_acc[g] = (f32x4){0.f, 0.f, 0.f, 0.f};

    for (int ii = 0; ii < TIS; ++ii) {
        const int i = strip * TIS + ii;

        AU au; au.u4 = make_uint4(0, 0, 0, 0);
        if (q < 2) {
            const float* wp = W + (((size_t)o * II + i) * 16 + n) * 16 + q * 8;
            float4 w0 = *(const float4*)(wp);
            float4 w1 = *(const float4*)(wp + 4);
            au.h[0]=f2bf(w0.x); au.h[1]=f2bf(w0.y); au.h[2]=f2bf(w0.z); au.h[3]=f2bf(w0.w);
            au.h[4]=f2bf(w1.x); au.h[5]=f2bf(w1.y); au.h[6]=f2bf(w1.z); au.h[7]=f2bf(w1.w);
        }

        f32x4 d4[4];
        #pragma unroll
        for (int g = 0; g < 4; ++g) {
            AU bu;
            bu.u4 = *reinterpret_cast<const uint4*>(
                ubf + ((size_t)i * 64 + g * 16 + n) * 16 + (q & 1) * 8);
            d4[g] = __builtin_amdgcn_mfma_f32_16x16x32_bf16(
                au.v, bu.v, (f32x4){0.f, 0.f, 0.f, 0.f}, 0, 0, 0);
        }

        #pragma unroll
        for (int g = 0; g < 4; ++g) {
            float n2 = d4[g][0]*d4[g][0] + d4[g][1]*d4[g][1]
                     + d4[g][2]*d4[g][2] + d4[g][3]*d4[g][3];
            n2 += __shfl_xor(n2, 16);
            n2 += __shfl_xor(n2, 32);
            const float rsq  = __builtin_amdgcn_rsqf(n2 + CAPS_EPS);
            const float rawn = n2 * rsq;
            const float un = unorm[(size_t)i * 64 + g * 16 + n];
            const float scale = fminf(rawn, un) * rsq;    // min/rawn

            YU yu;
            yu.h[0] = __float2half(scale * d4[g][0]);
            yu.h[1] = __float2half(scale * d4[g][1]);
            yu.h[2] = __float2half(scale * d4[g][2]);
            yu.h[3] = __float2half(scale * d4[g][3]);
            *reinterpret_cast<uint2*>(
                Y + (((size_t)i * OO + o) * 64 + g * 16 + n) * 16 + q * 4) = yu.u2;

            const float cs = 0.03125f * scale;            // c = 1/32 at r=0
            s_acc[g][0] += cs * d4[g][0];
            s_acc[g][1] += cs * d4[g][1];
            s_acc[g][2] += cs * d4[g][2];
            s_acc[g][3] += cs * d4[g][3];
        }
    }

    #pragma unroll
    for (int g = 0; g < 4; ++g) {
        P4 pu;
        pu.h[0] = __float2half(s_acc[g][0]);
        pu.h[1] = __float2half(s_acc[g][1]);
        pu.h[2] = __float2half(s_acc[g][2]);
        pu.h[3] = __float2half(s_acc[g][3]);
        *reinterpret_cast<uint2*>(
            part_h + (((size_t)strip * OO + o) * 64 + g * 16 + n) * 16 + q * 4) = pu.u2;
    }
}

// -------- fpart: parallel strip reduction, part fp16 -> p2[8][32768] f32 --------
template<int NS>
__global__ __launch_bounds__(256) void fpart_kernel(float* __restrict__ ws)
{
    const int tid = blockIdx.x * 256 + threadIdx.x;   // 262144
    const int g = tid >> 15;                          // 8 groups
    const int x = tid & 32767;                        // part inner index
    const __half* part_h = (const __half*)(ws + OFF_PART);
    constexpr int NSG = NS / 8;
    float s = 0.f;
    #pragma unroll
    for (int k = 0; k < NSG; ++k)
        s += __half2float(part_h[(size_t)(g * NSG + k) * 32768 + x]);
    ws[OFF_P2 + (size_t)g * 32768 + x] = s;
}

// -------- fsquash: sum p2 (+bias) -> squash -> v --------
// FINAL=0: write vt [O][B][D]; FINAL=1: write out [B][O][D]
template<int FINAL>
__global__ __launch_bounds__(256) void fsquash_kernel(
    float* __restrict__ ws, const float* __restrict__ bias,
    float* __restrict__ out)
{
    const int tid = blockIdx.x * 256 + threadIdx.x;  // 32768: b*512 + o*16 + d
    const int b = tid >> 9, o = (tid >> 4) & 31, d = tid & 15;
    const size_t px = ((size_t)o * 64 + b) * 16 + d;   // vt index
    float s = bias[tid & 511];
    #pragma unroll
    for (int g = 0; g < 8; ++g)
        s += ws[OFF_P2 + (size_t)g * 32768 + px];
    float n2 = s * s;
    #pragma unroll
    for (int off = 1; off < 16; off <<= 1) n2 += __shfl_xor(n2, off);
    const float val = s * n2 * __builtin_amdgcn_rcpf(1.f + n2)
                        * __builtin_amdgcn_rsqf(n2 + CAPS_EPS);
    if (FINAL) out[tid] = val;
    else       ws[OFF_VT + px] = val;
}

// -------- dpass: stream Y, dist fp16, block-reduced dsum --------
template<int SLOT>
__global__ __launch_bounds__(256) void dpass_kernel(float* __restrict__ ws)
{
    const int strip = blockIdx.x;           // NSTRIP
    const int og    = blockIdx.y;           // 8
    const int wave  = threadIdx.x >> 6;
    const int b     = threadIdx.x & 63;
    const int o     = og * 4 + wave;

    const __half* Y  = (const __half*)(ws + OFF_Y);
    const float* vt  = ws + OFF_VT;
    __half* dws = (__half*)(ws + OFF_DD);

    // coalesced v preload: 4 x float4 from [O][B][D]
    float v[16];
    {
        const float4* vp = reinterpret_cast<const float4*>(
            vt + ((size_t)o * 64 + b) * 16);
        float4 a = vp[0], c = vp[1], e = vp[2], f = vp[3];
        v[0]=a.x; v[1]=a.y; v[2]=a.z; v[3]=a.w;
        v[4]=c.x; v[5]=c.y; v[6]=c.z; v[7]=c.w;
        v[8]=e.x; v[9]=e.y; v[10]=e.z; v[11]=e.w;
        v[12]=f.x; v[13]=f.y; v[14]=f.z; v[15]=f.w;
    }
    float vn2 = 0.f;
    #pragma unroll
    for (int k = 0; k < 16; ++k) vn2 += v[k] * v[k];

    float acc = 0.f;
    #pragma unroll 4
    for (int s = 0; s < SLEN; ++s) {
        const int i = strip * SLEN + s;
        const uint4* yp = reinterpret_cast<const uint4*>(
            Y + (((size_t)i * OO + o) * 64 + b) * 16);
        YL yl;
        yl.u4[0] = yp[0];
        yl.u4[1] = yp[1];
        float dot = 0.f, yn2 = 0.f;
        #pragma unroll
        for (int k = 0; k < 16; ++k) {
            const float y = __half2float(yl.h[k]);
            dot += v[k] * y;
            yn2 += y * y;
        }
        const float dd2 = fmaxf(vn2 - 2.f * dot + yn2, 0.f);
        const __half dh = __float2half(__builtin_amdgcn_sqrtf(dd2));
        dws[((size_t)i * OO + o) * 64 + b] = dh;
        acc += __half2float(dh);
    }

    #pragma unroll
    for (int off = 32; off > 0; off >>= 1) acc += __shfl_down(acc, off);
    __shared__ float red[4];
    if ((threadIdx.x & 63) == 0) red[wave] = acc;
    __syncthreads();
    if (threadIdx.x == 0)
        atomicAdd(&ws[OFF_DSUM + SLOT], red[0] + red[1] + red[2] + red[3]);
}

// -------- csoft: rowmax + denom of softmax_o(t*d) per (i,b) --------
template<int SLOT>
__global__ __launch_bounds__(256) void csoft_kernel(float* __restrict__ ws)
{
    const int gid = blockIdx.x * 256 + threadIdx.x;   // 131072
    const int i = gid >> 6, b = gid & 63;

    const __half* dws = (const __half*)(ws + OFF_DD);
    const float dsum = ws[OFF_DSUM + SLOT];
    const float tval = T_CONST * __builtin_amdgcn_rcpf(
        -0.5f * dsum * (1.0f / 4194304.0f) + 1e-12f);

    float dv[OO];
    #pragma unroll
    for (int o = 0; o < OO; ++o)
        dv[o] = tval * __half2float(dws[((size_t)i * OO + o) * 64 + b]);
    float m = -1e30f;
    #pragma unroll
    for (int o = 0; o < OO; ++o) m = fmaxf(m, dv[o]);
    float den = 0.f;
    #pragma unroll
    for (int o = 0; o < OO; ++o) den += __expf(dv[o] - m);
    ws[OFF_TMAX + (size_t)i * 64 + b] = m;
    ws[OFF_TDEN + (size_t)i * 64 + b] = den;
}

// -------- spass: stream Y; fp16 partials --------
template<int SLOT>
__global__ __launch_bounds__(256) void spass_kernel(float* __restrict__ ws)
{
    const int strip = blockIdx.x;
    const int og    = blockIdx.y;
    const int wave  = threadIdx.x >> 6;
    const int b     = threadIdx.x & 63;
    const int o     = og * 4 + wave;

    const __half* Y = (const __half*)(ws + OFF_Y);
    const __half* dws = (const __half*)(ws + OFF_DD);
    const float* tmax = ws + OFF_TMAX;
    const float* tden = ws + OFF_TDEN;
    __half* part_h = (__half*)(ws + OFF_PART);

    const float dsum = ws[OFF_DSUM + SLOT];
    const float tval = T_CONST * __builtin_amdgcn_rcpf(
        -0.5f * dsum * (1.0f / 4194304.0f) + 1e-12f);

    float acc[16];
    #pragma unroll
    for (int k = 0; k < 16; ++k) acc[k] = 0.f;

    #pragma unroll 4
    for (int s = 0; s < SLEN; ++s) {
        const int i = strip * SLEN + s;
        const uint4* yp = reinterpret_cast<const uint4*>(
            Y + (((size_t)i * OO + o) * 64 + b) * 16);
        YL yl;
        yl.u4[0] = yp[0];
        yl.u4[1] = yp[1];
        const float d  = __half2float(dws[((size_t)i * OO + o) * 64 + b]);
        const float m  = tmax[(size_t)i * 64 + b];
        const float dn = tden[(size_t)i * 64 + b];
        const float p = __expf(tval * d - m) * __builtin_amdgcn_rcpf(dn);
        #pragma unroll
        for (int k = 0; k < 16; ++k)
            acc[k] += p * __half2float(yl.h[k]);
    }

    // fp16 coalesced partial store: part[strip][o][b][k] (wave = 2KB contig)
    PS su;
    #pragma unroll
    for (int k = 0; k < 16; ++k) su.h[k] = __float2half(acc[k]);
    uint4* pp = reinterpret_cast<uint4*>(
        part_h + (((size_t)strip * OO + o) * 64 + b) * 16);
    pp[0] = su.u4[0];
    pp[1] = su.u4[1];
}

// -------- transpose: c = softmax recompute, [I][O][B] -> out [B][O][I] --------
__global__ __launch_bounds__(256) void transpose_kernel(
    const float* __restrict__ ws, float* __restrict__ dst)
{
    __shared__ float tile[32][65];
    const __half* dws = (const __half*)(ws + OFF_DD);
    const float* tmax = ws + OFF_TMAX;
    const float* tden = ws + OFF_TDEN;
    const float dsum = ws[OFF_DSUM + 1];
    const float tval = T_CONST * __builtin_amdgcn_rcpf(
        -0.5f * dsum * (1.0f / 4194304.0f) + 1e-12f);

    const int o  = blockIdx.y;
    const int i0 = blockIdx.x * 32;
    #pragma unroll
    for (int k = 0; k < 8; ++k) {
        const int lin = k * 256 + threadIdx.x;
        const int r = lin >> 6, b = lin & 63;
        const int i = i0 + r;
        const float d = __half2float(dws[((size_t)i * OO + o) * 64 + b]);
        tile[r][b] = __expf(tval * d - tmax[(size_t)i * 64 + b])
                   * __builtin_amdgcn_rcpf(tden[(size_t)i * 64 + b]);
    }
    __syncthreads();
    #pragma unroll
    for (int k = 0; k < 8; ++k) {
        const int lin = k * 256 + threadIdx.x;
        const int b = lin >> 5, r = lin & 31;
        dst[((size_t)b * OO + o) * II + i0 + r] = tile[r][b];
    }
}

extern "C" void kernel_launch(void* const* d_in, const int* in_sizes, int n_in,
                              void* d_out, int out_size, void* d_ws, size_t ws_size,
                              hipStream_t stream) {
    const float* u    = (const float*)d_in[0];
    const float* W    = (const float*)d_in[1];
    const float* bias = (const float*)d_in[2];
    float* out = (float*)d_out;
    float* ws  = (float*)d_ws;

    float* cout = out + (size_t)BB * OO * DD;

    dim3 blk(256);
    dim3 grid_w(NSTRIP_W, 8);     // s0w: 2048 blocks
    dim3 grid_s(NSTRIP, 8);       // dpass/spass: 1024 blocks (proven)

    uprep_kernel<<<512, blk, 0, stream>>>(u, ws);
    s0w_kernel<<<grid_w, blk, 0, stream>>>(W, ws);
    fpart_kernel<NSTRIP_W><<<1024, blk, 0, stream>>>(ws);
    fsquash_kernel<0><<<128, blk, 0, stream>>>(ws, bias, out);
    dpass_kernel<0><<<grid_s, blk, 0, stream>>>(ws);
    csoft_kernel<0><<<512, blk, 0, stream>>>(ws);
    spass_kernel<0><<<grid_s, blk, 0, stream>>>(ws);
    fpart_kernel<NSTRIP><<<1024, blk, 0, stream>>>(ws);
    fsquash_kernel<0><<<128, blk, 0, stream>>>(ws, bias, out);
    dpass_kernel<1><<<grid_s, blk, 0, stream>>>(ws);
    csoft_kernel<1><<<512, blk, 0, stream>>>(ws);
    spass_kernel<1><<<grid_s, blk, 0, stream>>>(ws);
    fpart_kernel<NSTRIP><<<1024, blk, 0, stream>>>(ws);
    fsquash_kernel<1><<<128, blk, 0, stream>>>(ws, bias, out);
    transpose_kernel<<<dim3(64, 32), blk, 0, stream>>>(ws, cout);
}